// Round 12
// baseline (12564.500 us; speedup 1.0000x reference)
//
#include <hip/hip_runtime.h>
#include <stdint.h>

// SpikingNetwork B=128 T=128 I=1024 dims 2048/2048/1024, beta=0.9, thr=1.0.
// R16: attack the measured binder — LDS-read instruction throughput.
// Model (validated R10/R11/R15): dur ~= ds_read_b128/CU/t x 12cy. R11 = 8192
// instrs = 98K cy/t = 6.31ms. R15 proved occupancy does NOT help (42% occ,
// slower). R16: per-thread tile 8m x 4n (12 reads per 128 FMA vs R11's 8/64)
// -> 6144 instrs/CU/t -> ~74K cy -> ~4.9ms predicted. Geometry: 256 blocks x
// 256 thr (1 blk/CU, LDS 103KB), tile 128m x 64n, ONE 512-k chain per block:
// L0 32 tiles x ksplit2, L1 32 x 4, L2 16 x 4. All merges cross-block via
// R5's proven single-buffered global partials + tid0-spun flags; owner folds
// ((P0+P1)+P2)+P3 ascending. A-reads at tm*8 stride would be 4-way bank
// conflict -> extra swizzle col = m ^ (bit5(m)<<2) restores 2-way (free).
// DAG bit-identical to R5..R15: 512-k ascending fmac chains, __fadd_rn merges
// in order, LIF rounding verbatim. OccupancyPercent ~12.5 is EXPECTED.

#define TT   128
#define NB   128
#define DD2  1024

// ws layout (u32 units) — fits R4's proven 14,160,896 B budget
#define SPK0_OFF 0u
#define SPK1_OFF (128u*128u*64u)                 // 1,048,576
#define PART_OFF (2u*128u*128u*64u)              // 2,097,152
#define NHELP    176u                            // slots x 8192 floats (32KB)
#define FLG_OFF  (PART_OFF + NHELP*8192u)        // 3,538,944
#define NFLG     1024u                           // pflag176 oflag80 done0 128 done1 128 (+spare)
#define WS_NEED_BYTES ((size_t)(FLG_OFF + NFLG) * 4u)   // 14,159,872

__device__ __forceinline__ void wait_ge(uint32_t* p, uint32_t tgt){
  while (__hip_atomic_load(p, __ATOMIC_ACQUIRE, __HIP_MEMORY_SCOPE_AGENT) < tgt)
    __builtin_amdgcn_s_sleep(1);
}

// k-granule swizzle (as R11, multiples of 4, constant over 4-aligned k)
__device__ __forceinline__ constexpr int fswz(int k){
  return (k & 16) | ((k ^ (k >> 3)) & 12);
}
// m-column swizzle: flips bit2 by bit5 so the 16 m-octet read bases cover
// 8 distinct 16B positions mod 128B -> 2-way bank aliasing (free, m136)
#define COLQ(mb) ((mb) ^ ((((mb) >> 5) & 1) << 2))

__global__ void sentinel_kernel(float* o){ o[0] = 42.0f; }   // ws-too-small marker

__global__ __launch_bounds__(256, 1) void snn_kernel(
    const float* __restrict__ x,
    const float* __restrict__ W0, const float* __restrict__ b0,
    const float* __restrict__ W1, const float* __restrict__ b1,
    const float* __restrict__ W2, const float* __restrict__ b2,
    float* __restrict__ out, uint32_t* __restrict__ ws)
{
  __shared__ __align__(16) float lA[128][132];   // [k][colOf(m)^fswz], 67,584 B
  __shared__ __align__(16) float lB[128][68];    // [k][n^fswz],        34,816 B
  __shared__ uint32_t lBits[256];                // 128 rows x 2 words
  // total ~103.4 KB -> exactly 1 block/CU; 256 blocks all co-resident

  const int tid = threadIdx.x;
  const int tm  = tid & 15;      // m-octet: rows tm*8 .. +7
  const int tn  = tid >> 4;      // n-group: cols tn*4 .. +3  (0..15)
  const int bid = blockIdx.x;

  uint32_t* spikes0  = ws + SPK0_OFF;
  uint32_t* spikes1  = ws + SPK1_OFF;
  float*    partials = (float*)(ws + PART_OFF);   // [NHELP][8192]
  uint32_t* flg   = ws + FLG_OFF;
  uint32_t* pflag = flg;            // [176] helper(hslot)->owner: partial t ready
  uint32_t* oflag = flg + 176;      // [80]  owner(ownerid)->helpers: consumed t
  uint32_t* done0 = flg + 256;      // [128] t-counters, target 32
  uint32_t* done1 = flg + 384;      // [128] t-counters, target 32

  int group, kp, tl, n0, K, ksp, hslot, ownerid;
  const float *Wl, *bl;
  const uint32_t* spkIn; uint32_t* spkOut;
  uint32_t *dIn, *dOut;
  if (bid < 64) {           // L0: 32 tiles 128x64, K=1024, ksplit2
    group=0; ksp=2; kp=bid&1; tl=bid>>1;
    n0=tl*64; K=1024; Wl=W0; bl=b0;
    spkIn=nullptr; spkOut=spikes0; dIn=nullptr; dOut=done0;
    hslot = kp ? tl : -1; ownerid = tl;
  } else if (bid < 192) {   // L1: 32 tiles 128x64, K=2048, ksplit4
    group=1; ksp=4; int rel=bid-64; kp=rel&3; tl=rel>>2;
    n0=tl*64; K=2048; Wl=W1; bl=b1;
    spkIn=spikes0; spkOut=spikes1; dIn=done0; dOut=done1;
    hslot = kp ? (32 + tl*3 + (kp-1)) : -1; ownerid = 32 + tl;
  } else {                  // L2: 16 tiles 128x64, K=2048, ksplit4
    group=2; ksp=4; int rel=bid-192; kp=rel&3; tl=rel>>2;
    n0=tl*64; K=2048; Wl=W2; bl=b2;
    spkIn=spikes1; spkOut=nullptr; dIn=done1; dOut=nullptr;
    hslot = kp ? (128 + tl*3 + (kp-1)) : -1; ownerid = 64 + tl;
  }
  const bool owner = (kp == 0);
  const int  K0    = kp * 512;

  float bias[4];
  #pragma unroll
  for (int c = 0; c < 4; ++c) bias[c] = bl[n0 + tn*4 + c];

  float vst[8][4];   // membrane potential (owners)
  #pragma unroll
  for (int r = 0; r < 8; ++r)
    #pragma unroll
    for (int c = 0; c < 4; ++c) vst[r][c] = 0.f;

  // spike-expansion decomposition: 4 rows x 16 k per thread
  const int e_rq = tid & 31;        // row quad e_rq*4 .. +3 (128 rows)
  const int e_kg = tid >> 5;        // 16-k group (0..7)
  const int e_w  = e_kg >> 1;       // word within chunk (128k = 4 words)
  const int e_sb = (e_kg & 1) * 16; // bit base within word

  for (int t = 0; t < TT; ++t) {
    if (dIn) {  // all 32 producer tiles for this t (consumer spans full m,k)
      if (tid == 0) wait_ge(&dIn[t], 32u);
      __syncthreads();
    }

    float acc[8][4];   // ONE 512-k chain
    #pragma unroll
    for (int r = 0; r < 8; ++r)
      #pragma unroll
      for (int c = 0; c < 4; ++c) acc[r][c] = 0.f;

    #pragma unroll 1
    for (int ch = 0; ch < 4; ++ch) {            // 4 chunks of 128 k
      const int kb = K0 + ch*128;

      // ---- stage B: W[n][k] -> lB[k][n^fswz]  (64n x 128k)
      #pragma unroll
      for (int it = 0; it < 8; ++it) {
        int idx = tid + it*256;
        int nrow = idx >> 5, kq = idx & 31;
        float4 w = *(const float4*)(Wl + (size_t)(n0+nrow)*K + kb + kq*4);
        const int k0 = kq*4, sw = fswz(k0);
        const int col = nrow ^ sw;
        lB[k0+0][col] = w.x; lB[k0+1][col] = w.y;
        lB[k0+2][col] = w.z; lB[k0+3][col] = w.w;
      }

      // ---- stage A
      if (group == 0) {       // x[b,t,k] -> lA[k][colOf(m)^fswz]  (128m x 128k)
        #pragma unroll
        for (int it = 0; it < 16; ++it) {
          int idx = tid + it*256;
          int mrow = idx >> 5, kq = idx & 31;
          float4 v = *(const float4*)(x + ((size_t)mrow*TT + t)*1024 + kb + kq*4);
          const int k0 = kq*4, sw = fswz(k0);
          const int col = (mrow ^ (((mrow>>5)&1)<<2)) ^ sw;
          lA[k0+0][col] = v.x; lA[k0+1][col] = v.y;
          lA[k0+2][col] = v.z; lA[k0+3][col] = v.w;
        }
      } else {                // spike bits -> {0,1} f32; 4 rows x 16 k per thread
        const size_t rb = ((size_t)t*NB + e_rq*4)*64 + (kb>>5) + e_w;
        uint32_t w0 = __hip_atomic_load(&spkIn[rb      ], __ATOMIC_RELAXED, __HIP_MEMORY_SCOPE_AGENT);
        uint32_t w1 = __hip_atomic_load(&spkIn[rb +  64], __ATOMIC_RELAXED, __HIP_MEMORY_SCOPE_AGENT);
        uint32_t w2 = __hip_atomic_load(&spkIn[rb + 128], __ATOMIC_RELAXED, __HIP_MEMORY_SCOPE_AGENT);
        uint32_t w3 = __hip_atomic_load(&spkIn[rb + 192], __ATOMIC_RELAXED, __HIP_MEMORY_SCOPE_AGENT);
        const int colq = (e_rq*4) ^ (((e_rq>>3)&1)<<2);
        #pragma unroll
        for (int i = 0; i < 16; ++i) {
          const int k  = e_kg*16 + i;
          const int sh = e_sb + i;
          float4 f;
          f.x = ((w0 >> sh) & 1u) ? 1.0f : 0.0f;
          f.y = ((w1 >> sh) & 1u) ? 1.0f : 0.0f;
          f.z = ((w2 >> sh) & 1u) ? 1.0f : 0.0f;
          f.w = ((w3 >> sh) & 1u) ? 1.0f : 0.0f;
          *(float4*)&lA[k][colq ^ fswz(k)] = f;
        }
      }
      __syncthreads();

      // ---- FMA micro-kernel: 128 k x (8m x 4n), sequential ascending k
      #pragma unroll 4
      for (int k4 = 0; k4 < 32; ++k4) {
        const int kb4 = k4*4;
        const int sw  = fswz(kb4);            // constant over the 4 sub-ks
        const int qa  = COLQ(tm*8) ^ sw;
        const int qb  = (tn*4) ^ sw;
        #pragma unroll
        for (int u = 0; u < 4; ++u) {
          const float4 alo = *(const float4*)&lA[kb4+u][qa];     // rows tm*8+0..3
          const float4 ahi = *(const float4*)&lA[kb4+u][qa^4];   // rows tm*8+4..7
          const float4 bv  = *(const float4*)&lB[kb4+u][qb];
          const float ar[8] = {alo.x,alo.y,alo.z,alo.w, ahi.x,ahi.y,ahi.z,ahi.w};
          const float bc[4] = {bv.x,bv.y,bv.z,bv.w};
          #pragma unroll
          for (int r = 0; r < 8; ++r)
            #pragma unroll
            for (int c = 0; c < 4; ++c)
              acc[r][c] = __builtin_fmaf(ar[r], bc[c], acc[r][c]);
        }
      }
      __syncthreads();
    }

    if (!owner) {
      // ship P_kp; single-buffered vs owner's consumption of t-1
      if (t >= 1) { if (tid == 0) wait_ge(&oflag[ownerid], (uint32_t)t); __syncthreads(); }
      uint64_t* pb = (uint64_t*)(partials + (size_t)hslot*8192) + tid*16;
      #pragma unroll
      for (int r = 0; r < 8; ++r)
        #pragma unroll
        for (int cq = 0; cq < 2; ++cq) {
          union { float f[2]; uint64_t u; } cv;
          cv.f[0] = acc[r][cq*2+0]; cv.f[1] = acc[r][cq*2+1];
          __hip_atomic_store(&pb[r*2+cq], cv.u, __ATOMIC_RELAXED, __HIP_MEMORY_SCOPE_AGENT);
        }
      __syncthreads();
      if (tid == 0) __hip_atomic_store(&pflag[hslot], (uint32_t)(t+1), __ATOMIC_RELEASE, __HIP_MEMORY_SCOPE_AGENT);
      continue;
    }

    // ---- owner: fold P1 (, P2, P3) in ascending-k order (__fadd_rn)
    {
      if (tid == 0)
        for (int p = 1; p < ksp; ++p) {
          int hs = (group==0) ? tl : ((group==1) ? (32 + tl*3 + (p-1)) : (128 + tl*3 + (p-1)));
          wait_ge(&pflag[hs], (uint32_t)(t+1));
        }
      __syncthreads();
      for (int p = 1; p < ksp; ++p) {
        int hs = (group==0) ? tl : ((group==1) ? (32 + tl*3 + (p-1)) : (128 + tl*3 + (p-1)));
        uint64_t* pb = (uint64_t*)(partials + (size_t)hs*8192) + tid*16;
        #pragma unroll
        for (int r = 0; r < 8; ++r)
          #pragma unroll
          for (int cq = 0; cq < 2; ++cq) {
            union { uint64_t u; float f[2]; } cv;
            cv.u = __hip_atomic_load(&pb[r*2+cq], __ATOMIC_RELAXED, __HIP_MEMORY_SCOPE_AGENT);
            acc[r][cq*2+0] = __fadd_rn(acc[r][cq*2+0], cv.f[0]);
            acc[r][cq*2+1] = __fadd_rn(acc[r][cq*2+1], cv.f[1]);
          }
      }
      __syncthreads();
      if (tid == 0) __hip_atomic_store(&oflag[ownerid], (uint32_t)(t+1), __ATOMIC_RELEASE, __HIP_MEMORY_SCOPE_AGENT);
    }

    if (group < 2) { lBits[tid] = 0; __syncthreads(); }

    // LIF: cur = acc + b (rn); v = 0.9*v + cur (mul+add rn, NO fma contraction);
    // spk = v > 1.0 strictly; v -= spk.
    float sv[8][4], vv8[8][4];
    #pragma unroll
    for (int r = 0; r < 8; ++r) {
      uint32_t msk = 0;
      #pragma unroll
      for (int c = 0; c < 4; ++c) {
        float cur = __fadd_rn(acc[r][c], bias[c]);
        float vv  = __fadd_rn(__fmul_rn(0.9f, vst[r][c]), cur);
        float s   = (vv > 1.0f) ? 1.0f : 0.0f;
        vv = __fsub_rn(vv, s);
        vst[r][c] = vv;
        sv[r][c] = s; vv8[r][c] = vv;
        msk |= (s != 0.f) ? (1u << c) : 0u;
      }
      if (group < 2 && msk)
        atomicOr(&lBits[(tm*8 + r)*2 + (tn>>3)], msk << ((tn&7)*4));
    }

    if (group == 2) {
      #pragma unroll
      for (int r = 0; r < 8; ++r) {
        size_t o  = ((size_t)(tm*8 + r)*TT + t)*DD2 + n0 + tn*4;
        *(float4*)(out + o)  = make_float4(sv[r][0], sv[r][1], sv[r][2], sv[r][3]);
        size_t ov = (size_t)NB*TT*DD2 + o;
        *(float4*)(out + ov) = make_float4(vv8[r][0], vv8[r][1], vv8[r][2], vv8[r][3]);
      }
    } else {
      __syncthreads();
      {
        int row = tid >> 1, w = tid & 1;
        __hip_atomic_store(&spkOut[((size_t)t*NB + row)*64 + (n0>>5) + w],
                           lBits[tid], __ATOMIC_RELAXED, __HIP_MEMORY_SCOPE_AGENT);
      }
      __syncthreads();
      if (tid == 0) __hip_atomic_fetch_add(&dOut[t], 1u, __ATOMIC_RELEASE, __HIP_MEMORY_SCOPE_AGENT);
    }
  }
}

extern "C" void kernel_launch(void* const* d_in, const int* in_sizes, int n_in,
                              void* d_out, int out_size, void* d_ws, size_t ws_size,
                              hipStream_t stream) {
  (void)in_sizes; (void)n_in; (void)out_size;
  float* outf = (float*)d_out;
  if (ws_size < WS_NEED_BYTES) {            // diagnostic: absmax ~41 => ws too small
    sentinel_kernel<<<1, 1, 0, stream>>>(outf);
    return;
  }
  const float* x  = (const float*)d_in[0];
  const float* W0 = (const float*)d_in[1];
  const float* b0 = (const float*)d_in[2];
  const float* W1 = (const float*)d_in[3];
  const float* b1 = (const float*)d_in[4];
  const float* W2 = (const float*)d_in[5];
  const float* b2 = (const float*)d_in[6];
  uint32_t* ws = (uint32_t*)d_ws;

  // zero flags (spikes/partials are write-before-read; flags gate everything)
  hipMemsetAsync(ws + FLG_OFF, 0, NFLG * sizeof(uint32_t), stream);

  snn_kernel<<<256, 256, 0, stream>>>(x, W0, b0, W1, b1, W2, b2, outf, ws);
}

// Round 13
// 7479.941 us; speedup vs baseline: 1.6798x; 1.6798x over previous
//
#include <hip/hip_runtime.h>
#include <stdint.h>

// SpikingNetwork B=128 T=128 I=1024 dims 2048/2048/1024, beta=0.9, thr=1.0.
// R17: t-batched B-reuse on R11's proven geometry (6.31ms best). Weights are
// t-invariant -> stage B once per 4 timesteps; FMA against 4 t's A-tiles.
// LDS-read instrs/thread/t: 1024 -> 640 (the measured binder; model
// dur ~= instrs x 12cy at >=2 waves/SIMD — validated R10/R11/R15/R16).
// Geometry R11-verbatim: 256 blk x 512 thr (2 waves/SIMD), 64x64 tiles,
// in-block halves (h = k-part), L1/L2 cross-block pairs, coarse tid0-spun
// flags, per-t partial handshakes through 8192-float slots (WS layout
// identical). Chunk 32k: lA[2][4t][32][68]+lB[2][64][36]+lBits = 88.5KB,
// 1 blk/CU. DAG bit-identical to R5..R16: per-output 512-k ascending fmac
// chain (chunk-major, acc[tt] separate), ((P0+P1)+P2)+P3 __fadd_rn merges
// in order, LIF rounding verbatim, LIF sequential in t (vst in regs).
// Epilogue tt-loops FULLY unrolled (dynamic acc idx -> scratch, rule #20).

#define TT   128
#define NB   128
#define DD2  1024

// ws layout (u32 units) — identical to R11 (proven)
#define SPK0_OFF 0u
#define SPK1_OFF (128u*128u*64u)                 // 1,048,576
#define PART_OFF (2u*128u*128u*64u)              // 2,097,152
#define NHELP    96u                             // 96 slots x 8192 floats (32KB)
#define FLG_OFF  (PART_OFF + NHELP*8192u)        // 2,883,584
#define NFLG     1536u                           // pflag512 oflag512 done0 2x128 done1 2x128
#define WS_NEED_BYTES ((size_t)(FLG_OFF + NFLG) * 4u)   // 11,540,480

__device__ __forceinline__ void wait_ge(uint32_t* p, uint32_t tgt){
  while (__hip_atomic_load(p, __ATOMIC_ACQUIRE, __HIP_MEMORY_SCOPE_AGENT) < tgt)
    __builtin_amdgcn_s_sleep(1);
}

// LDS column swizzle for lA (R11-verbatim): 4-float granules, constant over a
// 4-aligned k-granule.
__device__ __forceinline__ constexpr int fswz(int k){
  return (k & 16) | ((k ^ (k >> 3)) & 12);
}

__global__ void sentinel_kernel(float* o){ o[0] = 42.0f; }   // ws-too-small marker

__global__ __launch_bounds__(512, 2) void snn_kernel(
    const float* __restrict__ x,
    const float* __restrict__ W0, const float* __restrict__ b0,
    const float* __restrict__ W1, const float* __restrict__ b1,
    const float* __restrict__ W2, const float* __restrict__ b2,
    float* __restrict__ out, uint32_t* __restrict__ ws)
{
  __shared__ __align__(16) float lA[2][4][32][68];  // [half][tt][k][m^swz], 69,632 B
  __shared__ __align__(16) float lB[2][64][36];     // [half][n][k+pad],     18,432 B
  __shared__ uint32_t lBits[128];                   // 64 rows x 2 words
  // total 88,576 B -> 1 block/CU; 256 blocks co-resident; 8 waves/CU (2/SIMD)

  const int tid  = threadIdx.x;
  const int h    = tid >> 8;       // half: k-part within block
  const int t256 = tid & 255;
  const int tm   = t256 & 15;      // m-group: rows tm*4 .. +3
  const int tn   = t256 >> 4;      // n-group: cols tn*4 .. +3
  const int bid  = blockIdx.x;

  uint32_t* spikes0  = ws + SPK0_OFF;
  uint32_t* spikes1  = ws + SPK1_OFF;
  float*    partials = (float*)(ws + PART_OFF);   // [NHELP][8192]
  uint32_t* flg   = ws + FLG_OFF;
  uint32_t* pflag = flg;            // [512] helper(bid)->owner: partials for t ready
  uint32_t* oflag = flg + 512;      // [512] owner(bid)->helper: consumed through t
  uint32_t* done0 = flg + 1024;     // [2][128] per m-half, target 32
  uint32_t* done1 = flg + 1280;     // [2][128] per m-half, target 32

  int group, pairk, tl, m0, n0, K, hslot;
  const float *Wl, *bl;
  const uint32_t* spkIn; uint32_t* spkOut;
  uint32_t *dIn, *dOut;
  if (bid < 64) {           // L0: 64 tiles 64x64, K=1024, ksplit2 in-block
    group=0; pairk=0; tl=bid;
    m0=(tl>>5)*64; n0=(tl&31)*64; K=1024; Wl=W0; bl=b0;
    spkIn=nullptr; spkOut=spikes0; dIn=nullptr; dOut=done0+(m0>>6)*128; hslot=-1;
  } else if (bid < 192) {   // L1: 64 tiles 64x64, K=2048, ksplit4 (2 blocks/tile)
    group=1; int rel=bid-64; pairk=rel&1; tl=rel>>1;
    m0=(tl>>5)*64; n0=(tl&31)*64; K=2048; Wl=W1; bl=b1;
    spkIn=spikes0; spkOut=spikes1;
    dIn=done0+(m0>>6)*128; dOut=done1+(m0>>6)*128; hslot=tl;
  } else {                  // L2: 32 tiles 64x64, K=2048, ksplit4
    group=2; int rel=bid-192; pairk=rel&1; tl=rel>>1;
    m0=(tl>>4)*64; n0=(tl&15)*64; K=2048; Wl=W2; bl=b2;
    spkIn=spikes1; spkOut=nullptr;
    dIn=done1+(m0>>6)*128; dOut=nullptr; hslot=64+tl;
  }
  const bool helper = (pairk == 1);   // odd block of a pair: ships P2,P3
  const int  K0     = (pairk*2 + h)*512;

  float bias[4];
  #pragma unroll
  for (int c = 0; c < 4; ++c) bias[c] = bl[n0 + tn*4 + c];

  float vst[4][4];   // membrane potential (owner h=0 threads)
  #pragma unroll
  for (int r = 0; r < 4; ++r)
    #pragma unroll
    for (int c = 0; c < 4; ++c) vst[r][c] = 0.f;

  // expansion decomposition: 1 row x 8 k (2 granules) per thread per tt
  const int e_row = t256 >> 2;       // 0..63
  const int e_g2  = (t256 & 3) * 2;  // granules e_g2, e_g2+1

  float (*cA)[32][68] = lA[h];
  float (*cB)[36]     = lB[h];
  float* ex = &lA[1][0][0][0];   // in-block merge buffer (16KB of half-1 lA)

  for (int t4 = 0; t4 < TT; t4 += 4) {
    if (dIn) {  // previous layer's spikes for the whole 4t-group
      if (tid == 0) {
        wait_ge(&dIn[t4+0], 32u); wait_ge(&dIn[t4+1], 32u);
        wait_ge(&dIn[t4+2], 32u); wait_ge(&dIn[t4+3], 32u);
      }
      __syncthreads();
    }

    float acc[4][4][4];   // [tt][r][c] — four independent 512-k chains
    #pragma unroll
    for (int tt = 0; tt < 4; ++tt)
      #pragma unroll
      for (int r = 0; r < 4; ++r)
        #pragma unroll
        for (int c = 0; c < 4; ++c) acc[tt][r][c] = 0.f;

    #pragma unroll 1
    for (int ch = 0; ch < 16; ++ch) {           // 16 chunks of 32 k
      const int kb = K0 + ch*32;

      // ---- stage B once per chunk (shared across the 4 t)
      #pragma unroll
      for (int it = 0; it < 2; ++it) {
        int idx = t256 + it*256;
        int nrow = idx >> 3, kq = idx & 7;
        float4 w = *(const float4*)(Wl + (size_t)(n0+nrow)*K + kb + kq*4);
        *(float4*)&cB[nrow][kq*4] = w;
      }

      // ---- stage A for all 4 t
      if (group == 0) {
        #pragma unroll
        for (int tt = 0; tt < 4; ++tt)
          #pragma unroll
          for (int it = 0; it < 2; ++it) {
            int idx = t256 + it*256;
            int mrow = idx >> 3, kq = idx & 7;
            float4 v = *(const float4*)(x + ((size_t)(m0+mrow)*TT + (t4+tt))*1024 + kb + kq*4);
            const int k0 = kq*4;
            const int col = mrow ^ fswz(k0);
            cA[tt][k0+0][col] = v.x; cA[tt][k0+1][col] = v.y;
            cA[tt][k0+2][col] = v.z; cA[tt][k0+3][col] = v.w;
          }
      } else {
        #pragma unroll
        for (int tt = 0; tt < 4; ++tt) {
          uint32_t w = __hip_atomic_load(
              &spkIn[((size_t)(t4+tt)*NB + m0 + e_row)*64 + (kb>>5)],
              __ATOMIC_RELAXED, __HIP_MEMORY_SCOPE_AGENT);
          #pragma unroll
          for (int gq = 0; gq < 2; ++gq) {
            const int k0  = (e_g2 + gq)*4;
            const int col = e_row ^ fswz(k0);
            cA[tt][k0+0][col] = ((w >> (k0+0)) & 1u) ? 1.0f : 0.0f;
            cA[tt][k0+1][col] = ((w >> (k0+1)) & 1u) ? 1.0f : 0.0f;
            cA[tt][k0+2][col] = ((w >> (k0+2)) & 1u) ? 1.0f : 0.0f;
            cA[tt][k0+3][col] = ((w >> (k0+3)) & 1u) ? 1.0f : 0.0f;
          }
        }
      }
      __syncthreads();

      // ---- FMA: 32 k x (4m x 4n) x 4 t; B read once per k4, A per t.
      #pragma unroll 2
      for (int k4 = 0; k4 < 8; ++k4) {
        const int kb4 = k4*4;
        const int sw  = fswz(kb4);
        const int qa  = (tm*4) ^ sw;
        const float4 q0 = *(const float4*)&cB[tn*4+0][kb4];
        const float4 q1 = *(const float4*)&cB[tn*4+1][kb4];
        const float4 q2 = *(const float4*)&cB[tn*4+2][kb4];
        const float4 q3 = *(const float4*)&cB[tn*4+3][kb4];
        #pragma unroll
        for (int u = 0; u < 4; ++u) {
          const float b0v = (u==0) ? q0.x : (u==1) ? q0.y : (u==2) ? q0.z : q0.w;
          const float b1v = (u==0) ? q1.x : (u==1) ? q1.y : (u==2) ? q1.z : q1.w;
          const float b2v = (u==0) ? q2.x : (u==1) ? q2.y : (u==2) ? q2.z : q2.w;
          const float b3v = (u==0) ? q3.x : (u==1) ? q3.y : (u==2) ? q3.z : q3.w;
          #pragma unroll
          for (int tt = 0; tt < 4; ++tt) {
            const float4 a = *(const float4*)&cA[tt][kb4+u][qa];
            acc[tt][0][0] = __builtin_fmaf(a.x, b0v, acc[tt][0][0]);
            acc[tt][1][0] = __builtin_fmaf(a.y, b0v, acc[tt][1][0]);
            acc[tt][2][0] = __builtin_fmaf(a.z, b0v, acc[tt][2][0]);
            acc[tt][3][0] = __builtin_fmaf(a.w, b0v, acc[tt][3][0]);
            acc[tt][0][1] = __builtin_fmaf(a.x, b1v, acc[tt][0][1]);
            acc[tt][1][1] = __builtin_fmaf(a.y, b1v, acc[tt][1][1]);
            acc[tt][2][1] = __builtin_fmaf(a.z, b1v, acc[tt][2][1]);
            acc[tt][3][1] = __builtin_fmaf(a.w, b1v, acc[tt][3][1]);
            acc[tt][0][2] = __builtin_fmaf(a.x, b2v, acc[tt][0][2]);
            acc[tt][1][2] = __builtin_fmaf(a.y, b2v, acc[tt][1][2]);
            acc[tt][2][2] = __builtin_fmaf(a.z, b2v, acc[tt][2][2]);
            acc[tt][3][2] = __builtin_fmaf(a.w, b2v, acc[tt][3][2]);
            acc[tt][0][3] = __builtin_fmaf(a.x, b3v, acc[tt][0][3]);
            acc[tt][1][3] = __builtin_fmaf(a.y, b3v, acc[tt][1][3]);
            acc[tt][2][3] = __builtin_fmaf(a.z, b3v, acc[tt][2][3]);
            acc[tt][3][3] = __builtin_fmaf(a.w, b3v, acc[tt][3][3]);
          }
        }
      }
      __syncthreads();
    }

    if (helper) {
      // ship P2 (h=0) / P3 (h=1), per-t through the single-buffered slot
      #pragma unroll
      for (int tt = 0; tt < 4; ++tt) {
        const int gt = t4 + tt;
        if (gt >= 1) { if (tid == 0) wait_ge(&oflag[bid-1], (uint32_t)gt); __syncthreads(); }
        uint64_t* pb = (uint64_t*)(partials + (size_t)hslot*8192 + (size_t)h*4096) + t256*8;
        #pragma unroll
        for (int r = 0; r < 4; ++r)
          #pragma unroll
          for (int cq = 0; cq < 2; ++cq) {
            union { float f[2]; uint64_t u; } cv;
            cv.f[0] = acc[tt][r][cq*2+0]; cv.f[1] = acc[tt][r][cq*2+1];
            __hip_atomic_store(&pb[r*2+cq], cv.u, __ATOMIC_RELAXED, __HIP_MEMORY_SCOPE_AGENT);
          }
        __syncthreads();
        if (tid == 0) __hip_atomic_store(&pflag[bid], (uint32_t)(gt+1), __ATOMIC_RELEASE, __HIP_MEMORY_SCOPE_AGENT);
      }
      continue;
    }

    // ---- owner epilogue, sequential per t (LIF order preserved)
    #pragma unroll
    for (int tt = 0; tt < 4; ++tt) {
      const int gt = t4 + tt;

      // in-block merge: acc = P0 + P1 (ascending, __fadd_rn)
      if (h == 1) {
        #pragma unroll
        for (int r = 0; r < 4; ++r)
          *(float4*)&ex[t256*16 + r*4] =
              make_float4(acc[tt][r][0], acc[tt][r][1], acc[tt][r][2], acc[tt][r][3]);
      }
      __syncthreads();
      float mg[4][4];
      if (h == 0) {
        #pragma unroll
        for (int r = 0; r < 4; ++r)
          #pragma unroll
          for (int c = 0; c < 4; ++c)
            mg[r][c] = __fadd_rn(acc[tt][r][c], ex[t256*16 + r*4 + c]);
      }

      // L1/L2: fold helper's P2 entirely, then P3 (same order as R5)
      if (group != 0) {
        if (tid == 0) wait_ge(&pflag[bid+1], (uint32_t)(gt+1));
        __syncthreads();
        if (h == 0) {
          uint64_t* p2 = (uint64_t*)(partials + (size_t)hslot*8192) + t256*8;
          uint64_t* p3 = (uint64_t*)(partials + (size_t)hslot*8192 + 4096) + t256*8;
          #pragma unroll
          for (int r = 0; r < 4; ++r)
            #pragma unroll
            for (int cq = 0; cq < 2; ++cq) {
              union { uint64_t u; float f[2]; } cv;
              cv.u = __hip_atomic_load(&p2[r*2+cq], __ATOMIC_RELAXED, __HIP_MEMORY_SCOPE_AGENT);
              mg[r][cq*2+0] = __fadd_rn(mg[r][cq*2+0], cv.f[0]);
              mg[r][cq*2+1] = __fadd_rn(mg[r][cq*2+1], cv.f[1]);
            }
          #pragma unroll
          for (int r = 0; r < 4; ++r)
            #pragma unroll
            for (int cq = 0; cq < 2; ++cq) {
              union { uint64_t u; float f[2]; } cv;
              cv.u = __hip_atomic_load(&p3[r*2+cq], __ATOMIC_RELAXED, __HIP_MEMORY_SCOPE_AGENT);
              mg[r][cq*2+0] = __fadd_rn(mg[r][cq*2+0], cv.f[0]);
              mg[r][cq*2+1] = __fadd_rn(mg[r][cq*2+1], cv.f[1]);
            }
        }
        __syncthreads();
        if (tid == 0) __hip_atomic_store(&oflag[bid], (uint32_t)(gt+1), __ATOMIC_RELEASE, __HIP_MEMORY_SCOPE_AGENT);
      }

      if (group < 2) { if (tid < 128) lBits[tid] = 0; __syncthreads(); }

      // LIF: cur = mg + b (rn); v = 0.9*v + cur (mul+add rn, NO fma
      // contraction); spk = v > 1.0 strictly; v -= spk.
      if (h == 0) {
        float sv[4][4], vv8[4][4];
        #pragma unroll
        for (int r = 0; r < 4; ++r) {
          uint32_t msk = 0;
          #pragma unroll
          for (int c = 0; c < 4; ++c) {
            float cur = __fadd_rn(mg[r][c], bias[c]);
            float vv  = __fadd_rn(__fmul_rn(0.9f, vst[r][c]), cur);
            float s   = (vv > 1.0f) ? 1.0f : 0.0f;
            vv = __fsub_rn(vv, s);
            vst[r][c] = vv;
            sv[r][c] = s; vv8[r][c] = vv;
            msk |= (s != 0.f) ? (1u << c) : 0u;
          }
          if (group < 2 && msk)
            atomicOr(&lBits[(tm*4 + r)*2 + (tn>>3)], msk << ((tn&7)*4));
        }
        if (group == 2) {
          #pragma unroll
          for (int r = 0; r < 4; ++r) {
            size_t o  = ((size_t)(m0 + tm*4 + r)*TT + gt)*DD2 + n0 + tn*4;
            *(float4*)(out + o)  = make_float4(sv[r][0], sv[r][1], sv[r][2], sv[r][3]);
            size_t ov = (size_t)NB*TT*DD2 + o;
            *(float4*)(out + ov) = make_float4(vv8[r][0], vv8[r][1], vv8[r][2], vv8[r][3]);
          }
        }
      }

      if (group < 2) {
        __syncthreads();
        if (tid < 128)
          __hip_atomic_store(&spkOut[((size_t)gt*NB + m0 + (tid>>1))*64 + (n0>>5) + (tid&1)],
                             lBits[tid], __ATOMIC_RELAXED, __HIP_MEMORY_SCOPE_AGENT);
        __syncthreads();
        if (tid == 0) __hip_atomic_fetch_add(&dOut[gt], 1u, __ATOMIC_RELEASE, __HIP_MEMORY_SCOPE_AGENT);
      }
    }
  }
}

extern "C" void kernel_launch(void* const* d_in, const int* in_sizes, int n_in,
                              void* d_out, int out_size, void* d_ws, size_t ws_size,
                              hipStream_t stream) {
  (void)in_sizes; (void)n_in; (void)out_size;
  float* outf = (float*)d_out;
  if (ws_size < WS_NEED_BYTES) {            // diagnostic: absmax ~41 => ws too small
    sentinel_kernel<<<1, 1, 0, stream>>>(outf);
    return;
  }
  const float* x  = (const float*)d_in[0];
  const float* W0 = (const float*)d_in[1];
  const float* b0 = (const float*)d_in[2];
  const float* W1 = (const float*)d_in[3];
  const float* b1 = (const float*)d_in[4];
  const float* W2 = (const float*)d_in[5];
  const float* b2 = (const float*)d_in[6];
  uint32_t* ws = (uint32_t*)d_ws;

  // zero flags (spikes/partials are write-before-read; flags gate everything)
  hipMemsetAsync(ws + FLG_OFF, 0, NFLG * sizeof(uint32_t), stream);

  snn_kernel<<<256, 512, 0, stream>>>(x, W0, b0, W1, b1, W2, b2, outf, ws);
}

// Round 14
// 6873.746 us; speedup vs baseline: 1.8279x; 1.0882x over previous
//
#include <hip/hip_runtime.h>
#include <stdint.h>

// SpikingNetwork B=128 T=128 I=1024 dims 2048/2048/1024, beta=0.9, thr=1.0.
// R18: R17's t-batched B-reuse with the register fix. R17 (tt=4, acc=64 VGPR)
// hit the 128-VGPR cap -> compiler couldn't pipeline ds_reads -> latency-
// exposed FMA (VALUBusy 51->32, dur 7.48). R18: tt=2 (acc[2][4][4]=32 VGPR),
// chunk 64k (same 8 barriers/t as R11), lA[2][2][64][68]+lB[2][64][68] =
// ~102.5KB -> 1 blk/CU, 2 waves/SIMD (R11's proven regime). LDS reads/t =
// 768 (0.75x R11) WITH scheduler headroom. Geometry/flags/partials/LIF:
// R11/R17-verbatim. DAG bit-identical: per-output 512-k ascending fmac chain
// (chunk-major, acc[tt] separate, fully-unrolled tt), ((P0+P1)+P2)+P3
// __fadd_rn merges in order, LIF rounding verbatim, sequential in t.

#define TT   128
#define NB   128
#define DD2  1024

// ws layout (u32 units) — identical to R11 (proven)
#define SPK0_OFF 0u
#define SPK1_OFF (128u*128u*64u)                 // 1,048,576
#define PART_OFF (2u*128u*128u*64u)              // 2,097,152
#define NHELP    96u                             // 96 slots x 8192 floats (32KB)
#define FLG_OFF  (PART_OFF + NHELP*8192u)        // 2,883,584
#define NFLG     1536u                           // pflag512 oflag512 done0 2x128 done1 2x128
#define WS_NEED_BYTES ((size_t)(FLG_OFF + NFLG) * 4u)   // 11,540,480

__device__ __forceinline__ void wait_ge(uint32_t* p, uint32_t tgt){
  while (__hip_atomic_load(p, __ATOMIC_ACQUIRE, __HIP_MEMORY_SCOPE_AGENT) < tgt)
    __builtin_amdgcn_s_sleep(1);
}

// LDS column swizzle for lA (R11-verbatim): 4-float granules, constant over a
// 4-aligned k-granule.
__device__ __forceinline__ constexpr int fswz(int k){
  return (k & 16) | ((k ^ (k >> 3)) & 12);
}

__global__ void sentinel_kernel(float* o){ o[0] = 42.0f; }   // ws-too-small marker

__global__ __launch_bounds__(512, 2) void snn_kernel(
    const float* __restrict__ x,
    const float* __restrict__ W0, const float* __restrict__ b0,
    const float* __restrict__ W1, const float* __restrict__ b1,
    const float* __restrict__ W2, const float* __restrict__ b2,
    float* __restrict__ out, uint32_t* __restrict__ ws)
{
  __shared__ __align__(16) float lA[2][2][64][68];  // [half][tt][k][m^swz], 69,632 B
  __shared__ __align__(16) float lB[2][64][68];     // [half][n][k+pad],     34,816 B
  __shared__ uint32_t lBits[128];                   // 64 rows x 2 words
  // total ~104.9 KB -> 1 block/CU; 256 blocks co-resident; 8 waves/CU (2/SIMD)

  const int tid  = threadIdx.x;
  const int h    = tid >> 8;       // half: k-part within block
  const int t256 = tid & 255;
  const int tm   = t256 & 15;      // m-group: rows tm*4 .. +3
  const int tn   = t256 >> 4;      // n-group: cols tn*4 .. +3
  const int bid  = blockIdx.x;

  uint32_t* spikes0  = ws + SPK0_OFF;
  uint32_t* spikes1  = ws + SPK1_OFF;
  float*    partials = (float*)(ws + PART_OFF);   // [NHELP][8192]
  uint32_t* flg   = ws + FLG_OFF;
  uint32_t* pflag = flg;            // [512] helper(bid)->owner: partials for t ready
  uint32_t* oflag = flg + 512;      // [512] owner(bid)->helper: consumed through t
  uint32_t* done0 = flg + 1024;     // [2][128] per m-half, target 32
  uint32_t* done1 = flg + 1280;     // [2][128] per m-half, target 32

  int group, pairk, tl, m0, n0, K, hslot;
  const float *Wl, *bl;
  const uint32_t* spkIn; uint32_t* spkOut;
  uint32_t *dIn, *dOut;
  if (bid < 64) {           // L0: 64 tiles 64x64, K=1024, ksplit2 in-block
    group=0; pairk=0; tl=bid;
    m0=(tl>>5)*64; n0=(tl&31)*64; K=1024; Wl=W0; bl=b0;
    spkIn=nullptr; spkOut=spikes0; dIn=nullptr; dOut=done0+(m0>>6)*128; hslot=-1;
  } else if (bid < 192) {   // L1: 64 tiles 64x64, K=2048, ksplit4 (2 blocks/tile)
    group=1; int rel=bid-64; pairk=rel&1; tl=rel>>1;
    m0=(tl>>5)*64; n0=(tl&31)*64; K=2048; Wl=W1; bl=b1;
    spkIn=spikes0; spkOut=spikes1;
    dIn=done0+(m0>>6)*128; dOut=done1+(m0>>6)*128; hslot=tl;
  } else {                  // L2: 32 tiles 64x64, K=2048, ksplit4
    group=2; int rel=bid-192; pairk=rel&1; tl=rel>>1;
    m0=(tl>>4)*64; n0=(tl&15)*64; K=2048; Wl=W2; bl=b2;
    spkIn=spikes1; spkOut=nullptr;
    dIn=done1+(m0>>6)*128; dOut=nullptr; hslot=64+tl;
  }
  const bool helper = (pairk == 1);   // odd block of a pair: ships P2,P3
  const int  K0     = (pairk*2 + h)*512;

  float bias[4];
  #pragma unroll
  for (int c = 0; c < 4; ++c) bias[c] = bl[n0 + tn*4 + c];

  float vst[4][4];   // membrane potential (owner h=0 threads)
  #pragma unroll
  for (int r = 0; r < 4; ++r)
    #pragma unroll
    for (int c = 0; c < 4; ++c) vst[r][c] = 0.f;

  // spike expansion: 1 row x 16 k (4 granules, one word) per thread per tt
  const int e_row = t256 >> 2;       // 0..63
  const int e_sub = t256 & 3;        // 16-k segment within 64-k chunk

  float (*cA)[64][68] = lA[h];
  float (*cB)[68]     = lB[h];
  float* ex = &lA[1][0][0][0];   // in-block merge buffer (16KB of half-1 lA)

  for (int t2 = 0; t2 < TT; t2 += 2) {
    if (dIn) {  // previous layer's spikes for both t of this group
      if (tid == 0) { wait_ge(&dIn[t2+0], 32u); wait_ge(&dIn[t2+1], 32u); }
      __syncthreads();
    }

    float acc[2][4][4];   // [tt][r][c] — two independent 512-k chains (32 VGPR)
    #pragma unroll
    for (int tt = 0; tt < 2; ++tt)
      #pragma unroll
      for (int r = 0; r < 4; ++r)
        #pragma unroll
        for (int c = 0; c < 4; ++c) acc[tt][r][c] = 0.f;

    #pragma unroll 1
    for (int ch = 0; ch < 8; ++ch) {            // 8 chunks of 64 k
      const int kb = K0 + ch*64;

      // ---- stage B once per chunk (shared across the 2 t)
      #pragma unroll
      for (int it = 0; it < 4; ++it) {
        int idx = t256 + it*256;
        int nrow = idx >> 4, kq = idx & 15;
        float4 w = *(const float4*)(Wl + (size_t)(n0+nrow)*K + kb + kq*4);
        *(float4*)&cB[nrow][kq*4] = w;
      }

      // ---- stage A for both t
      if (group == 0) {
        #pragma unroll
        for (int tt = 0; tt < 2; ++tt)
          #pragma unroll
          for (int it = 0; it < 4; ++it) {
            int idx = t256 + it*256;
            int mrow = idx >> 4, kq = idx & 15;
            float4 v = *(const float4*)(x + ((size_t)(m0+mrow)*TT + (t2+tt))*1024 + kb + kq*4);
            const int k0 = kq*4;
            const int col = mrow ^ fswz(k0);
            cA[tt][k0+0][col] = v.x; cA[tt][k0+1][col] = v.y;
            cA[tt][k0+2][col] = v.z; cA[tt][k0+3][col] = v.w;
          }
      } else {                // spike bits -> {0,1} f32; 1 row x 16 k per tt
        #pragma unroll
        for (int tt = 0; tt < 2; ++tt) {
          uint32_t w = __hip_atomic_load(
              &spkIn[((size_t)(t2+tt)*NB + m0 + e_row)*64 + (kb>>5) + (e_sub>>1)],
              __ATOMIC_RELAXED, __HIP_MEMORY_SCOPE_AGENT);
          #pragma unroll
          for (int gq = 0; gq < 4; ++gq) {
            const int k0  = e_sub*16 + gq*4;       // local 0..63
            const int sh  = k0 & 31;
            const int col = e_row ^ fswz(k0);
            cA[tt][k0+0][col] = ((w >> (sh+0)) & 1u) ? 1.0f : 0.0f;
            cA[tt][k0+1][col] = ((w >> (sh+1)) & 1u) ? 1.0f : 0.0f;
            cA[tt][k0+2][col] = ((w >> (sh+2)) & 1u) ? 1.0f : 0.0f;
            cA[tt][k0+3][col] = ((w >> (sh+3)) & 1u) ? 1.0f : 0.0f;
          }
        }
      }
      __syncthreads();

      // ---- FMA: 64 k x (4m x 4n) x 2 t; B read once per k4, A per t.
      #pragma unroll 4
      for (int k4 = 0; k4 < 16; ++k4) {
        const int kb4 = k4*4;
        const int sw  = fswz(kb4);
        const int qa  = (tm*4) ^ sw;
        const float4 q0 = *(const float4*)&cB[tn*4+0][kb4];
        const float4 q1 = *(const float4*)&cB[tn*4+1][kb4];
        const float4 q2 = *(const float4*)&cB[tn*4+2][kb4];
        const float4 q3 = *(const float4*)&cB[tn*4+3][kb4];
        #pragma unroll
        for (int u = 0; u < 4; ++u) {
          const float b0v = (u==0) ? q0.x : (u==1) ? q0.y : (u==2) ? q0.z : q0.w;
          const float b1v = (u==0) ? q1.x : (u==1) ? q1.y : (u==2) ? q1.z : q1.w;
          const float b2v = (u==0) ? q2.x : (u==1) ? q2.y : (u==2) ? q2.z : q2.w;
          const float b3v = (u==0) ? q3.x : (u==1) ? q3.y : (u==2) ? q3.z : q3.w;
          #pragma unroll
          for (int tt = 0; tt < 2; ++tt) {
            const float4 a = *(const float4*)&cA[tt][kb4+u][qa];
            acc[tt][0][0] = __builtin_fmaf(a.x, b0v, acc[tt][0][0]);
            acc[tt][1][0] = __builtin_fmaf(a.y, b0v, acc[tt][1][0]);
            acc[tt][2][0] = __builtin_fmaf(a.z, b0v, acc[tt][2][0]);
            acc[tt][3][0] = __builtin_fmaf(a.w, b0v, acc[tt][3][0]);
            acc[tt][0][1] = __builtin_fmaf(a.x, b1v, acc[tt][0][1]);
            acc[tt][1][1] = __builtin_fmaf(a.y, b1v, acc[tt][1][1]);
            acc[tt][2][1] = __builtin_fmaf(a.z, b1v, acc[tt][2][1]);
            acc[tt][3][1] = __builtin_fmaf(a.w, b1v, acc[tt][3][1]);
            acc[tt][0][2] = __builtin_fmaf(a.x, b2v, acc[tt][0][2]);
            acc[tt][1][2] = __builtin_fmaf(a.y, b2v, acc[tt][1][2]);
            acc[tt][2][2] = __builtin_fmaf(a.z, b2v, acc[tt][2][2]);
            acc[tt][3][2] = __builtin_fmaf(a.w, b2v, acc[tt][3][2]);
            acc[tt][0][3] = __builtin_fmaf(a.x, b3v, acc[tt][0][3]);
            acc[tt][1][3] = __builtin_fmaf(a.y, b3v, acc[tt][1][3]);
            acc[tt][2][3] = __builtin_fmaf(a.z, b3v, acc[tt][2][3]);
            acc[tt][3][3] = __builtin_fmaf(a.w, b3v, acc[tt][3][3]);
          }
        }
      }
      __syncthreads();
    }

    if (helper) {
      // ship P2 (h=0) / P3 (h=1), per-t through the single-buffered slot
      #pragma unroll
      for (int tt = 0; tt < 2; ++tt) {
        const int gt = t2 + tt;
        if (gt >= 1) { if (tid == 0) wait_ge(&oflag[bid-1], (uint32_t)gt); __syncthreads(); }
        uint64_t* pb = (uint64_t*)(partials + (size_t)hslot*8192 + (size_t)h*4096) + t256*8;
        #pragma unroll
        for (int r = 0; r < 4; ++r)
          #pragma unroll
          for (int cq = 0; cq < 2; ++cq) {
            union { float f[2]; uint64_t u; } cv;
            cv.f[0] = acc[tt][r][cq*2+0]; cv.f[1] = acc[tt][r][cq*2+1];
            __hip_atomic_store(&pb[r*2+cq], cv.u, __ATOMIC_RELAXED, __HIP_MEMORY_SCOPE_AGENT);
          }
        __syncthreads();
        if (tid == 0) __hip_atomic_store(&pflag[bid], (uint32_t)(gt+1), __ATOMIC_RELEASE, __HIP_MEMORY_SCOPE_AGENT);
      }
      continue;
    }

    // ---- owner epilogue, sequential per t (LIF order preserved)
    #pragma unroll
    for (int tt = 0; tt < 2; ++tt) {
      const int gt = t2 + tt;

      // in-block merge: acc = P0 + P1 (ascending, __fadd_rn)
      if (h == 1) {
        #pragma unroll
        for (int r = 0; r < 4; ++r)
          *(float4*)&ex[t256*16 + r*4] =
              make_float4(acc[tt][r][0], acc[tt][r][1], acc[tt][r][2], acc[tt][r][3]);
      }
      __syncthreads();
      float mg[4][4];
      if (h == 0) {
        #pragma unroll
        for (int r = 0; r < 4; ++r)
          #pragma unroll
          for (int c = 0; c < 4; ++c)
            mg[r][c] = __fadd_rn(acc[tt][r][c], ex[t256*16 + r*4 + c]);
      }

      // L1/L2: fold helper's P2 entirely, then P3 (same order as R5)
      if (group != 0) {
        if (tid == 0) wait_ge(&pflag[bid+1], (uint32_t)(gt+1));
        __syncthreads();
        if (h == 0) {
          uint64_t* p2 = (uint64_t*)(partials + (size_t)hslot*8192) + t256*8;
          uint64_t* p3 = (uint64_t*)(partials + (size_t)hslot*8192 + 4096) + t256*8;
          #pragma unroll
          for (int r = 0; r < 4; ++r)
            #pragma unroll
            for (int cq = 0; cq < 2; ++cq) {
              union { uint64_t u; float f[2]; } cv;
              cv.u = __hip_atomic_load(&p2[r*2+cq], __ATOMIC_RELAXED, __HIP_MEMORY_SCOPE_AGENT);
              mg[r][cq*2+0] = __fadd_rn(mg[r][cq*2+0], cv.f[0]);
              mg[r][cq*2+1] = __fadd_rn(mg[r][cq*2+1], cv.f[1]);
            }
          #pragma unroll
          for (int r = 0; r < 4; ++r)
            #pragma unroll
            for (int cq = 0; cq < 2; ++cq) {
              union { uint64_t u; float f[2]; } cv;
              cv.u = __hip_atomic_load(&p3[r*2+cq], __ATOMIC_RELAXED, __HIP_MEMORY_SCOPE_AGENT);
              mg[r][cq*2+0] = __fadd_rn(mg[r][cq*2+0], cv.f[0]);
              mg[r][cq*2+1] = __fadd_rn(mg[r][cq*2+1], cv.f[1]);
            }
        }
        __syncthreads();
        if (tid == 0) __hip_atomic_store(&oflag[bid], (uint32_t)(gt+1), __ATOMIC_RELEASE, __HIP_MEMORY_SCOPE_AGENT);
      }

      if (group < 2) { if (tid < 128) lBits[tid] = 0; __syncthreads(); }

      // LIF: cur = mg + b (rn); v = 0.9*v + cur (mul+add rn, NO fma
      // contraction); spk = v > 1.0 strictly; v -= spk.
      if (h == 0) {
        float sv[4][4], vv8[4][4];
        #pragma unroll
        for (int r = 0; r < 4; ++r) {
          uint32_t msk = 0;
          #pragma unroll
          for (int c = 0; c < 4; ++c) {
            float cur = __fadd_rn(mg[r][c], bias[c]);
            float vv  = __fadd_rn(__fmul_rn(0.9f, vst[r][c]), cur);
            float s   = (vv > 1.0f) ? 1.0f : 0.0f;
            vv = __fsub_rn(vv, s);
            vst[r][c] = vv;
            sv[r][c] = s; vv8[r][c] = vv;
            msk |= (s != 0.f) ? (1u << c) : 0u;
          }
          if (group < 2 && msk)
            atomicOr(&lBits[(tm*4 + r)*2 + (tn>>3)], msk << ((tn&7)*4));
        }
        if (group == 2) {
          #pragma unroll
          for (int r = 0; r < 4; ++r) {
            size_t o  = ((size_t)(m0 + tm*4 + r)*TT + gt)*DD2 + n0 + tn*4;
            *(float4*)(out + o)  = make_float4(sv[r][0], sv[r][1], sv[r][2], sv[r][3]);
            size_t ov = (size_t)NB*TT*DD2 + o;
            *(float4*)(out + ov) = make_float4(vv8[r][0], vv8[r][1], vv8[r][2], vv8[r][3]);
          }
        }
      }

      if (group < 2) {
        __syncthreads();
        if (tid < 128)
          __hip_atomic_store(&spkOut[((size_t)gt*NB + m0 + (tid>>1))*64 + (n0>>5) + (tid&1)],
                             lBits[tid], __ATOMIC_RELAXED, __HIP_MEMORY_SCOPE_AGENT);
        __syncthreads();
        if (tid == 0) __hip_atomic_fetch_add(&dOut[gt], 1u, __ATOMIC_RELEASE, __HIP_MEMORY_SCOPE_AGENT);
      }
    }
  }
}

extern "C" void kernel_launch(void* const* d_in, const int* in_sizes, int n_in,
                              void* d_out, int out_size, void* d_ws, size_t ws_size,
                              hipStream_t stream) {
  (void)in_sizes; (void)n_in; (void)out_size;
  float* outf = (float*)d_out;
  if (ws_size < WS_NEED_BYTES) {            // diagnostic: absmax ~41 => ws too small
    sentinel_kernel<<<1, 1, 0, stream>>>(outf);
    return;
  }
  const float* x  = (const float*)d_in[0];
  const float* W0 = (const float*)d_in[1];
  const float* b0 = (const float*)d_in[2];
  const float* W1 = (const float*)d_in[3];
  const float* b1 = (const float*)d_in[4];
  const float* W2 = (const float*)d_in[5];
  const float* b2 = (const float*)d_in[6];
  uint32_t* ws = (uint32_t*)d_ws;

  // zero flags (spikes/partials are write-before-read; flags gate everything)
  hipMemsetAsync(ws + FLG_OFF, 0, NFLG * sizeof(uint32_t), stream);

  snn_kernel<<<256, 512, 0, stream>>>(x, W0, b0, W1, b1, W2, b2, outf, ws);
}